// Round 8
// baseline (931.851 us; speedup 1.0000x reference)
//
#include <hip/hip_runtime.h>

constexpr int kNR = 40000;
constexpr int kNU = 30000;
constexpr int kNP = 30000;
constexpr int kN  = 100000;          // total nodes
constexpr int kE  = 1600000;         // edges
constexpr int kF  = 128;             // feature/hidden dim
constexpr int kC  = 40;              // classes
constexpr int kSB = 98;              // ceil(kN/1024) scan blocks
constexpr int kAS = 32;              // agg row stride (27 used; 128B rows)
constexpr int kBN = 256;             // nodes per bucket
constexpr int kNB = (kN + kBN - 1) / kBN;   // 391 buckets
constexpr int kCap = 4608;           // edge capacity per bucket (avg 4096, +5.6 sigma)

typedef __attribute__((ext_vector_type(8))) short bf16x8;   // 4 VGPRs: MFMA A/B frag
typedef __attribute__((ext_vector_type(4))) float f32x4;    // MFMA C/D frag

// ---------- bf16 helpers (storage-only; math in fp32) ----------
__device__ __forceinline__ float bf_to_f(unsigned short h) {
    union { unsigned int i; float f; } u; u.i = ((unsigned int)h) << 16; return u.f;
}
__device__ __forceinline__ unsigned short f_to_bf(float f) {
    union { unsigned int i; float f; } u; u.f = f;
    unsigned int r = u.i + 0x7FFFu + ((u.i >> 16) & 1u);   // round-nearest-even
    return (unsigned short)(r >> 16);
}
__device__ __forceinline__ float2 bf2_to_f2(unsigned int p) {
    union { unsigned int i; float f; } lo, hi;
    lo.i = (p & 0xFFFFu) << 16;
    hi.i = p & 0xFFFF0000u;
    return make_float2(lo.f, hi.f);
}
__device__ __forceinline__ unsigned int pack_bf2(float a, float b) {
    return (unsigned int)f_to_bf(a) | ((unsigned int)f_to_bf(b) << 16);
}
__device__ __forceinline__ float ldf(const void* p, int i, int isbf) {
    return isbf ? bf_to_f(((const unsigned short*)p)[i]) : ((const float*)p)[i];
}
__device__ __forceinline__ int lde(const int* p, int i, int is64) {
    return is64 ? p[2 * i] : p[i];
}

// ---------- sniff dtypes -> flags[0]=isbf, flags[1]=is64 ----------
__global__ void gcn_sniff(const unsigned int* __restrict__ w1w,
                          const int* __restrict__ eiw, int* __restrict__ flags) {
    if (blockIdx.x != 0 || threadIdx.x != 0) return;
    int plaus = 0;
    for (int k = 0; k < 64; k++) {
        unsigned int ax = w1w[k] & 0x7FFFu;
        plaus += (ax == 0u) || (ax > 0x2000u && ax < 0x4000u);
    }
    flags[0] = (plaus >= 48) ? 1 : 0;
    int nz = 0;
    for (int k = 0; k < 64; k++) nz |= eiw[2 * k + 1];
    flags[1] = (nz == 0) ? 1 : 0;
}

__global__ void gcn_zero_i32(int* __restrict__ p, int n) {
    int i = blockIdx.x * 256 + threadIdx.x;
    if (i < n) p[i] = 0;
}

__global__ void gcn_initb(int* __restrict__ cbuc) {
    int i = blockIdx.x * 256 + threadIdx.x;
    if (i < kNB) cbuc[i] = i * kCap;
}

// ---------- fused weights, TRANSPOSED bf16: fwT[feat(128)][slot(32)] ----------
// slots 0-4: Wr@W1 | 8-14: Wu@W1 | 16-21: Wp@W1 | 24/25/26: br/bu/bp @W1 | rest 0
__global__ void gcn_fuse(const void* __restrict__ Wr, const void* __restrict__ br,
                         const void* __restrict__ Wu, const void* __restrict__ bu,
                         const void* __restrict__ Wp, const void* __restrict__ bp,
                         const void* __restrict__ W1, unsigned short* __restrict__ fwT,
                         const int* __restrict__ flags) {
    __shared__ float sw[21 * kF];    // rows 0-4 Wr, 5-11 Wu, 12-17 Wp, 18 br, 19 bu, 20 bp
    int isbf = flags[0];
    int t = threadIdx.x;             // 128 threads
    for (int i = t; i < 21 * kF; i += 128) {
        int r = i >> 7, c = i & 127;
        float v;
        if (r < 5)        v = ldf(Wr, r * kF + c, isbf);
        else if (r < 12)  v = ldf(Wu, (r - 5) * kF + c, isbf);
        else if (r < 18)  v = ldf(Wp, (r - 12) * kF + c, isbf);
        else if (r == 18) v = ldf(br, c, isbf);
        else if (r == 19) v = ldf(bu, c, isbf);
        else              v = ldf(bp, c, isbf);
        sw[i] = v;
    }
    __syncthreads();
    int j = t;                       // output column (feature) of W1
    float acc[21];
    #pragma unroll
    for (int r = 0; r < 21; r++) acc[r] = 0.f;
    for (int k = 0; k < kF; k++) {
        float w1 = ldf(W1, k * kF + j, isbf);
        #pragma unroll
        for (int r = 0; r < 21; r++) acc[r] += sw[r * kF + k] * w1;
    }
    unsigned short row[32];
    #pragma unroll
    for (int s = 0; s < 32; s++) row[s] = 0;
    #pragma unroll
    for (int i = 0; i < 5; i++) row[0  + i] = f_to_bf(acc[i]);
    #pragma unroll
    for (int i = 0; i < 7; i++) row[8  + i] = f_to_bf(acc[5 + i]);
    #pragma unroll
    for (int i = 0; i < 6; i++) row[16 + i] = f_to_bf(acc[12 + i]);
    row[24] = f_to_bf(acc[18]);  row[25] = f_to_bf(acc[19]);  row[26] = f_to_bf(acc[20]);
    #pragma unroll
    for (int s = 0; s < 32; s++) fwT[j * 32 + s] = row[s];
}

// ---------- pack raw features: xpack[n] = uint4 of 8 bf16 (zero-padded) ----------
__global__ void __launch_bounds__(256) gcn_pack(const void* __restrict__ xr,
                                                const void* __restrict__ xu,
                                                const void* __restrict__ xp,
                                                uint4* __restrict__ xpack,
                                                const int* __restrict__ flags) {
    int isbf = flags[0];
    int n = blockIdx.x * 256 + threadIdx.x;
    if (n >= kN) return;
    const void* base; int roff, d;
    if (n < kNR)            { base = xr; roff = n * 5;               d = 5; }
    else if (n < kNR + kNU) { base = xu; roff = (n - kNR) * 7;       d = 7; }
    else                    { base = xp; roff = (n - kNR - kNU) * 6; d = 6; }
    float f[8];
    #pragma unroll
    for (int i = 0; i < 8; i++) f[i] = (i < d) ? ldf(base, roff + i, isbf) : 0.f;
    uint4 u;
    u.x = pack_bf2(f[0], f[1]);  u.y = pack_bf2(f[2], f[3]);
    u.z = pack_bf2(f[4], f[5]);  u.w = pack_bf2(f[6], f[7]);
    xpack[n] = u;
}

// ---------- Phase A: fused node-histogram + bucket multisplit ----------
// One pass over edges. Frontier-append to 391 bucket regions -> writes cluster at
// moving frontiers -> full-line evictions (fixes R7's 73MB partial-line WRITE).
__global__ void __launch_bounds__(256) gcn_bucket(const int* __restrict__ ei,
                                                  int* __restrict__ cnt,
                                                  int* __restrict__ cbuc,
                                                  unsigned int* __restrict__ pairs,
                                                  const int* __restrict__ flags) {
    int is64 = flags[1];
    int stride = gridDim.x * 256;
    for (int e = blockIdx.x * 256 + (int)threadIdx.x; e < kE; e += stride) {
        unsigned int d = (unsigned int)lde(ei, kE + e, is64);
        if (d < (unsigned int)kN) {
            atomicAdd(&cnt[d], 1);
            unsigned int s = (unsigned int)lde(ei, e, is64);
            if (s >= (unsigned int)kN) s = 0;
            int b = d >> 8;
            int p = atomicAdd(&cbuc[b], 1);
            if (p < (b + 1) * kCap)                       // overflow -> rescan fallback
                pairs[p] = (s << 8) | (d & 255u);         // s<2^17, dloc 8 bits
        }
    }
}

// ---------- scans (rp only) ----------
__global__ void gcn_scan1(const int* __restrict__ cnt, int* __restrict__ bsums) {
    __shared__ int lds[256];
    int t = threadIdx.x;
    int base = blockIdx.x * 1024 + t * 4;
    int s = 0;
    #pragma unroll
    for (int j = 0; j < 4; j++) { int i = base + j; s += (i < kN) ? cnt[i] : 0; }
    lds[t] = s; __syncthreads();
    for (int o = 128; o > 0; o >>= 1) {
        if (t < o) lds[t] += lds[t + o];
        __syncthreads();
    }
    if (t == 0) bsums[blockIdx.x] = lds[0];
}

__global__ void gcn_scan2(int* __restrict__ bsums, int* __restrict__ rp) {
    __shared__ int lds[128];
    int t = threadIdx.x;
    int v = (t < kSB) ? bsums[t] : 0;
    int incl = v; lds[t] = incl; __syncthreads();
    for (int o = 1; o < 128; o <<= 1) {
        int y = (t >= o) ? lds[t - o] : 0;
        __syncthreads();
        incl += y; lds[t] = incl;
        __syncthreads();
    }
    if (t < kSB) bsums[t] = incl - v;
    if (t == 127) rp[kN] = incl;
}

__global__ void gcn_scan3(const int* __restrict__ cnt, const int* __restrict__ bsums,
                          int* __restrict__ rp) {
    __shared__ int lds[256];
    int t = threadIdx.x;
    int base = blockIdx.x * 1024 + t * 4;
    int v0 = (base + 0 < kN) ? cnt[base + 0] : 0;
    int v1 = (base + 1 < kN) ? cnt[base + 1] : 0;
    int v2 = (base + 2 < kN) ? cnt[base + 2] : 0;
    int v3 = (base + 3 < kN) ? cnt[base + 3] : 0;
    int s = v0 + v1 + v2 + v3;
    int incl = s; lds[t] = incl; __syncthreads();
    for (int o = 1; o < 256; o <<= 1) {
        int y = (t >= o) ? lds[t - o] : 0;
        __syncthreads();
        incl += y; lds[t] = incl;
        __syncthreads();
    }
    int excl = incl - s + bsums[blockIdx.x];
    if (base + 0 < kN) rp[base + 0] = excl;  excl += v0;
    if (base + 1 < kN) rp[base + 1] = excl;  excl += v1;
    if (base + 2 < kN) rp[base + 2] = excl;  excl += v2;
    if (base + 3 < kN) rp[base + 3] = excl;
}

// ---------- Phase B: per-bucket CSR col build + fused layer-1 raw aggregation ----------
// Block b owns nodes [b*256, b*256+256): LDS cursors, LDS col staging (coalesced flush),
// LDS fp32 agg accumulation (ds_add_f32), xpack gather from L2-resident 1.6MB table.
__global__ void __launch_bounds__(256) GCN_2190433321521_kernel(
        const unsigned int* __restrict__ pairs,
        const int* __restrict__ cbuc,
        const int* __restrict__ rp,
        const int* __restrict__ ei,
        const uint4* __restrict__ xpack,
        int* __restrict__ col,
        float* __restrict__ agg,
        const int* __restrict__ flags) {
    __shared__ float agg_l[kBN][28];    // 28.7 KB
    __shared__ int   cur_l[kBN];        // 1 KB
    __shared__ int   col_l[kCap];       // 18.4 KB
    int b = blockIdx.x;
    int base = b * kBN;
    int nn = min(kBN, kN - base);
    int tid = threadIdx.x;
    float* aflat = (float*)agg_l;
    for (int i = tid; i < kBN * 28; i += 256) aflat[i] = 0.f;
    for (int i = tid; i < nn; i += 256) cur_l[i] = rp[base + i];
    __syncthreads();
    int rp0 = rp[base];
    int cnt_b = cbuc[b] - b * kCap;

    auto process = [&](unsigned int s, int dloc) {
        int sb = (s < (unsigned int)kNR) ? 0 : ((s < (unsigned int)(kNR + kNU)) ? 8 : 16);
        uint4 u = xpack[s];
        float2 p0 = bf2_to_f2(u.x), p1 = bf2_to_f2(u.y);
        float2 p2 = bf2_to_f2(u.z), p3 = bf2_to_f2(u.w);
        float* a = &agg_l[dloc][sb];
        atomicAdd(&a[0], p0.x); atomicAdd(&a[1], p0.y);
        atomicAdd(&a[2], p1.x); atomicAdd(&a[3], p1.y);
        atomicAdd(&a[4], p2.x); atomicAdd(&a[5], p2.y);
        atomicAdd(&a[6], p3.x); atomicAdd(&a[7], p3.y);
        atomicAdd(&agg_l[dloc][24 + (sb >> 3)], 1.f);
    };

    if (cnt_b <= kCap) {
        const unsigned int* pb = pairs + b * kCap;
        for (int i = tid; i < cnt_b; i += 256) {
            unsigned int w = pb[i];
            unsigned int s = w >> 8;
            int dloc = (int)(w & 255u);
            int pos = atomicAdd(&cur_l[dloc], 1);
            col_l[pos - rp0] = (int)s;
            process(s, dloc);
        }
        __syncthreads();
        for (int i = tid; i < cnt_b; i += 256) col[rp0 + i] = col_l[i];  // coalesced
    } else {
        // pathological overflow: rescan whole edge list for this bucket (correct, slow)
        int is64 = flags[1];
        for (int e = tid; e < kE; e += 256) {
            unsigned int d = (unsigned int)lde(ei, kE + e, is64);
            if (d >= (unsigned int)base && d < (unsigned int)(base + nn)) {
                unsigned int s = (unsigned int)lde(ei, e, is64);
                if (s >= (unsigned int)kN) s = 0;
                int dloc = (int)(d - base);
                int pos = atomicAdd(&cur_l[dloc], 1);
                col[pos] = (int)s;
                process(s, dloc);
            }
        }
        __syncthreads();
    }
    // flush agg rows (slots 27..31 zero), coalesced 128B rows
    for (int i = tid; i < nn * 32; i += 256) {
        int n = i >> 5, sl = i & 31;
        agg[(size_t)(base + n) * kAS + sl] = (sl < 27) ? agg_l[n][sl] : 0.f;
    }
}

// ---------- dense via MFMA: one wave per 16 nodes ----------
__global__ void __launch_bounds__(256) gcn_dense(const float* __restrict__ agg,
                                                 const unsigned short* __restrict__ fwT,
                                                 const void* __restrict__ W2,
                                                 unsigned short* __restrict__ hw,
                                                 const int* __restrict__ flags) {
    __shared__ __align__(16) unsigned short sfwT[kF][40];
    __shared__ __align__(16) unsigned short sw2T[48][136];
    __shared__ __align__(16) unsigned short hbuf[4][16][136];
    int isbf = flags[0];
    int tid = threadIdx.x;
    for (int i = tid; i < kF * 32; i += 256) sfwT[i >> 5][i & 31] = fwT[i];
    for (int i = tid; i < 48 * kF; i += 256) {
        int c = i >> 7, k = i & 127;
        sw2T[c][k] = (c < kC) ? f_to_bf(ldf(W2, k * kC + c, isbf)) : (unsigned short)0;
    }
    __syncthreads();
    int wid = tid >> 6, lane = tid & 63;
    int T = blockIdx.x * 4 + wid;
    if (T >= kN / 16) return;
    int n0 = T * 16;
    int m = lane & 15, q = lane >> 4;

    const float* ar = agg + (size_t)(n0 + m) * kAS + q * 8;
    bf16x8 a1;
    #pragma unroll
    for (int i = 0; i < 8; i++) a1[i] = (short)f_to_bf(ar[i]);

    f32x4 c1[8];
    #pragma unroll
    for (int t = 0; t < 8; t++) {
        bf16x8 bfr = *(const bf16x8*)&sfwT[16 * t + m][q * 8];
        f32x4 z = {0.f, 0.f, 0.f, 0.f};
        c1[t] = __builtin_amdgcn_mfma_f32_16x16x32_bf16(a1, bfr, z, 0, 0, 0);
    }
    #pragma unroll
    for (int t = 0; t < 8; t++) {
        #pragma unroll
        for (int r = 0; r < 4; r++)
            hbuf[wid][q * 4 + r][16 * t + m] = f_to_bf(fmaxf(c1[t][r], 0.f));
    }
    f32x4 c2[3];
    #pragma unroll
    for (int t = 0; t < 3; t++) { c2[t].x = 0.f; c2[t].y = 0.f; c2[t].z = 0.f; c2[t].w = 0.f; }
    #pragma unroll
    for (int s = 0; s < 4; s++) {
        bf16x8 a2 = *(const bf16x8*)&hbuf[wid][m][s * 32 + q * 8];
        #pragma unroll
        for (int t = 0; t < 3; t++) {
            bf16x8 b2 = *(const bf16x8*)&sw2T[16 * t + m][s * 32 + q * 8];
            c2[t] = __builtin_amdgcn_mfma_f32_16x16x32_bf16(a2, b2, c2[t], 0, 0, 0);
        }
    }
    #pragma unroll
    for (int t = 0; t < 3; t++) {
        int cls = 16 * t + m;
        if (cls < kC) {
            #pragma unroll
            for (int r = 0; r < 4; r++)
                hw[(size_t)(n0 + q * 4 + r) * kC + cls] = f_to_bf(c2[t][r]);
        }
    }
}

// ---------- layer-2 gather: 3 edge-groups x 20 class-lanes per wave ----------
__global__ void __launch_bounds__(256) gcn_gather2(const unsigned int* __restrict__ hw32,
                                                   const int* __restrict__ rp,
                                                   const int* __restrict__ col,
                                                   unsigned int* __restrict__ out,
                                                   const int* __restrict__ flags) {
    int isbf = flags[0];
    int w = (blockIdx.x * 256 + threadIdx.x) >> 6;
    if (w >= kN) return;
    int lane = threadIdx.x & 63;
    int grp = lane / 20;
    int c2  = lane % 20;
    int beg = rp[w], end = rp[w + 1];
    float ax = 0.f, ay = 0.f;
    if (grp < 3) {
        int e = beg + grp;
        for (; e + 3 < end; e += 6) {
            float2 f0 = bf2_to_f2(hw32[col[e]     * 20 + c2]);
            float2 f1 = bf2_to_f2(hw32[col[e + 3] * 20 + c2]);
            ax += f0.x + f1.x;  ay += f0.y + f1.y;
        }
        if (e < end) {
            float2 f = bf2_to_f2(hw32[col[e] * 20 + c2]);
            ax += f.x; ay += f.y;
        }
    }
    ax += __shfl(ax, lane + 20, 64) + __shfl(ax, lane + 40, 64);
    ay += __shfl(ay, lane + 20, 64) + __shfl(ay, lane + 40, 64);
    if (lane < 20) {
        if (isbf) {
            out[w * 20 + lane] = pack_bf2(ax, ay);
        } else {
            float* of = (float*)out;
            of[w * 40 + 2*lane]     = ax;
            of[w * 40 + 2*lane + 1] = ay;
        }
    }
}

extern "C" void kernel_launch(void* const* d_in, const int* in_sizes, int n_in,
                              void* d_out, int out_size, void* d_ws, size_t ws_size,
                              hipStream_t stream) {
    const void* xr = d_in[0];
    const void* xu = d_in[1];
    const void* xp = d_in[2];
    const int*  ei = (const int*)d_in[3];
    const void* Wr = d_in[4];
    const void* br = d_in[5];
    const void* Wu = d_in[6];
    const void* bu = d_in[7];
    const void* Wp = d_in[8];
    const void* bp = d_in[9];
    const void* W1 = d_in[10];
    const void* W2 = d_in[11];
    (void)in_sizes; (void)n_in; (void)out_size; (void)ws_size;

    char* ws = (char*)d_ws;
    size_t off = 0;
    auto alloc = [&](size_t bytes) -> void* {
        void* p = (void*)(ws + off);
        off = (off + bytes + 255) & ~(size_t)255;
        return p;
    };
    int*            flags = (int*)           alloc(256);
    int*            rp    = (int*)           alloc((size_t)(kN + 1) * 4);
    int*            cnt   = (int*)           alloc((size_t)kN * 4);
    int*            cbuc  = (int*)           alloc((size_t)kNB * 4);
    int*            bs    = (int*)           alloc(128 * 4);
    unsigned short* fwT   = (unsigned short*)alloc(kF * 32 * 2);             // 8 KB
    uint4*          xpack = (uint4*)         alloc((size_t)kN * 16);         // 1.6 MB
    unsigned int*   pairs = (unsigned int*)  alloc((size_t)kNB * kCap * 4);  // 7.2 MB
    int*            col   = (int*)           alloc((size_t)kE * 4);          // 6.4 MB
    unsigned short* hwb   = (unsigned short*)alloc((size_t)kN * kC * 2);     // 8 MB
    float*          agg   = (float*)         alloc((size_t)kN * kAS * 4);    // 12.8 MB

    gcn_sniff<<<1, 64, 0, stream>>>((const unsigned int*)W1, ei, flags);
    gcn_zero_i32<<<(kN + 255) / 256, 256, 0, stream>>>(cnt, kN);
    gcn_initb<<<(kNB + 255) / 256, 256, 0, stream>>>(cbuc);
    gcn_fuse<<<1, 128, 0, stream>>>(Wr, br, Wu, bu, Wp, bp, W1, fwT, flags);
    gcn_pack<<<(kN + 255) / 256, 256, 0, stream>>>(xr, xu, xp, xpack, flags);
    gcn_bucket<<<1024, 256, 0, stream>>>(ei, cnt, cbuc, pairs, flags);
    gcn_scan1<<<kSB, 256, 0, stream>>>(cnt, bs);
    gcn_scan2<<<1, 128, 0, stream>>>(bs, rp);
    gcn_scan3<<<kSB, 256, 0, stream>>>(cnt, bs, rp);
    GCN_2190433321521_kernel<<<kNB, 256, 0, stream>>>(pairs, cbuc, rp, ei, xpack,
                                                      col, agg, flags);
    gcn_dense<<<(kN / 16 + 3) / 4, 256, 0, stream>>>(agg, fwT, W2, hwb, flags);
    gcn_gather2<<<(kN * 64 + 255) / 256, 256, 0, stream>>>((const unsigned int*)hwb, rp, col,
                                                           (unsigned int*)d_out, flags);
}

// Round 9
// 705.227 us; speedup vs baseline: 1.3213x; 1.3213x over previous
//
#include <hip/hip_runtime.h>

constexpr int kNR = 40000;
constexpr int kNU = 30000;
constexpr int kNP = 30000;
constexpr int kN  = 100000;          // total nodes
constexpr int kE  = 1600000;         // edges
constexpr int kF  = 128;             // feature/hidden dim
constexpr int kC  = 40;              // classes
constexpr int kAS = 32;              // agg row stride (27 used; 128B rows)
constexpr int kBN = 256;             // nodes per bucket
constexpr int kNB = (kN + kBN - 1) / kBN;   // 391 buckets
constexpr int kCH = 256;             // edge chunks
constexpr int kCE = kE / kCH;        // 6250 edges per chunk (exact)

typedef __attribute__((ext_vector_type(8))) short bf16x8;   // 4 VGPRs: MFMA A/B frag
typedef __attribute__((ext_vector_type(4))) float f32x4;    // MFMA C/D frag

// ---------- bf16 helpers (storage-only; math in fp32) ----------
__device__ __forceinline__ float bf_to_f(unsigned short h) {
    union { unsigned int i; float f; } u; u.i = ((unsigned int)h) << 16; return u.f;
}
__device__ __forceinline__ unsigned short f_to_bf(float f) {
    union { unsigned int i; float f; } u; u.f = f;
    unsigned int r = u.i + 0x7FFFu + ((u.i >> 16) & 1u);   // round-nearest-even
    return (unsigned short)(r >> 16);
}
__device__ __forceinline__ float2 bf2_to_f2(unsigned int p) {
    union { unsigned int i; float f; } lo, hi;
    lo.i = (p & 0xFFFFu) << 16;
    hi.i = p & 0xFFFF0000u;
    return make_float2(lo.f, hi.f);
}
__device__ __forceinline__ unsigned int pack_bf2(float a, float b) {
    return (unsigned int)f_to_bf(a) | ((unsigned int)f_to_bf(b) << 16);
}
__device__ __forceinline__ float ldf(const void* p, int i, int isbf) {
    return isbf ? bf_to_f(((const unsigned short*)p)[i]) : ((const float*)p)[i];
}
__device__ __forceinline__ int lde(const int* p, int i, int is64) {
    return is64 ? p[2 * i] : p[i];
}

// ---------- sniff dtypes -> flags[0]=isbf, flags[1]=is64 ----------
__global__ void gcn_sniff(const unsigned int* __restrict__ w1w,
                          const int* __restrict__ eiw, int* __restrict__ flags) {
    if (blockIdx.x != 0 || threadIdx.x != 0) return;
    int plaus = 0;
    for (int k = 0; k < 64; k++) {
        unsigned int ax = w1w[k] & 0x7FFFu;
        plaus += (ax == 0u) || (ax > 0x2000u && ax < 0x4000u);
    }
    flags[0] = (plaus >= 48) ? 1 : 0;
    int nz = 0;
    for (int k = 0; k < 64; k++) nz |= eiw[2 * k + 1];
    flags[1] = (nz == 0) ? 1 : 0;
}

// ---------- fused weights, TRANSPOSED bf16: fwT[feat(128)][slot(32)] ----------
__global__ void gcn_fuse(const void* __restrict__ Wr, const void* __restrict__ br,
                         const void* __restrict__ Wu, const void* __restrict__ bu,
                         const void* __restrict__ Wp, const void* __restrict__ bp,
                         const void* __restrict__ W1, unsigned short* __restrict__ fwT,
                         const int* __restrict__ flags) {
    __shared__ float sw[21 * kF];
    int isbf = flags[0];
    int t = threadIdx.x;             // 128 threads
    for (int i = t; i < 21 * kF; i += 128) {
        int r = i >> 7, c = i & 127;
        float v;
        if (r < 5)        v = ldf(Wr, r * kF + c, isbf);
        else if (r < 12)  v = ldf(Wu, (r - 5) * kF + c, isbf);
        else if (r < 18)  v = ldf(Wp, (r - 12) * kF + c, isbf);
        else if (r == 18) v = ldf(br, c, isbf);
        else if (r == 19) v = ldf(bu, c, isbf);
        else              v = ldf(bp, c, isbf);
        sw[i] = v;
    }
    __syncthreads();
    int j = t;
    float acc[21];
    #pragma unroll
    for (int r = 0; r < 21; r++) acc[r] = 0.f;
    for (int k = 0; k < kF; k++) {
        float w1 = ldf(W1, k * kF + j, isbf);
        #pragma unroll
        for (int r = 0; r < 21; r++) acc[r] += sw[r * kF + k] * w1;
    }
    unsigned short row[32];
    #pragma unroll
    for (int s = 0; s < 32; s++) row[s] = 0;
    #pragma unroll
    for (int i = 0; i < 5; i++) row[0  + i] = f_to_bf(acc[i]);
    #pragma unroll
    for (int i = 0; i < 7; i++) row[8  + i] = f_to_bf(acc[5 + i]);
    #pragma unroll
    for (int i = 0; i < 6; i++) row[16 + i] = f_to_bf(acc[12 + i]);
    row[24] = f_to_bf(acc[18]);  row[25] = f_to_bf(acc[19]);  row[26] = f_to_bf(acc[20]);
    #pragma unroll
    for (int s = 0; s < 32; s++) fwT[j * 32 + s] = row[s];
}

// ---------- pack raw features: xpack[n] = uint4 of 8 bf16 (zero-padded) ----------
__global__ void __launch_bounds__(256) gcn_pack(const void* __restrict__ xr,
                                                const void* __restrict__ xu,
                                                const void* __restrict__ xp,
                                                uint4* __restrict__ xpack,
                                                const int* __restrict__ flags) {
    int isbf = flags[0];
    int n = blockIdx.x * 256 + threadIdx.x;
    if (n >= kN) return;
    const void* base; int roff, d;
    if (n < kNR)            { base = xr; roff = n * 5;               d = 5; }
    else if (n < kNR + kNU) { base = xu; roff = (n - kNR) * 7;       d = 7; }
    else                    { base = xp; roff = (n - kNR - kNU) * 6; d = 6; }
    float f[8];
    #pragma unroll
    for (int i = 0; i < 8; i++) f[i] = (i < d) ? ldf(base, roff + i, isbf) : 0.f;
    uint4 u;
    u.x = pack_bf2(f[0], f[1]);  u.y = pack_bf2(f[2], f[3]);
    u.z = pack_bf2(f[4], f[5]);  u.w = pack_bf2(f[6], f[7]);
    xpack[n] = u;
}

// ---------- multisplit pass 1: per-chunk bucket counts -> cmat[chunk][400] ----------
__global__ void __launch_bounds__(512) gcn_count(const int* __restrict__ ei,
                                                 int* __restrict__ cmat,
                                                 const int* __restrict__ flags) {
    __shared__ int cl[400];
    int is64 = flags[1];
    int blk = blockIdx.x, t = threadIdx.x;
    for (int i = t; i < 400; i += 512) cl[i] = 0;
    __syncthreads();
    int e0 = blk * kCE, e1 = e0 + kCE;
    for (int e = e0 + t; e < e1; e += 512) {
        unsigned int d = (unsigned int)lde(ei, kE + e, is64);
        if (d < (unsigned int)kN) atomicAdd(&cl[d >> 8], 1);
    }
    __syncthreads();
    for (int i = t; i < 400; i += 512) cmat[blk * 400 + i] = cl[i];   // coalesced
}

// ---------- pass 2a: per-bucket scan over chunks -> reloff[b][chunk], btot[b] ----------
__global__ void gcn_scanB1(const int* __restrict__ cmat, int* __restrict__ reloff,
                           int* __restrict__ btot) {
    __shared__ int lds[256];
    int b = blockIdx.x, t = threadIdx.x;
    int v = cmat[t * 400 + b];
    int incl = v; lds[t] = incl; __syncthreads();
    for (int o = 1; o < 256; o <<= 1) {
        int y = (t >= o) ? lds[t - o] : 0;
        __syncthreads();
        incl += y; lds[t] = incl;
        __syncthreads();
    }
    reloff[b * 256 + t] = incl - v;
    if (t == 255) btot[b] = incl;
}

// ---------- pass 2b: scan 391 bucket totals -> bbase[0..391] ----------
__global__ void gcn_scanB2(const int* __restrict__ btot, int* __restrict__ bbase) {
    __shared__ int lds[256];
    int t = threadIdx.x;
    int i0 = 2 * t, i1 = 2 * t + 1;
    int v0 = (i0 < kNB) ? btot[i0] : 0;
    int v1 = (i1 < kNB) ? btot[i1] : 0;
    int s = v0 + v1;
    int incl = s; lds[t] = incl; __syncthreads();
    for (int o = 1; o < 256; o <<= 1) {
        int y = (t >= o) ? lds[t - o] : 0;
        __syncthreads();
        incl += y; lds[t] = incl;
        __syncthreads();
    }
    int excl = incl - s;
    if (i0 < kNB) bbase[i0] = excl;
    if (i1 < kNB) bbase[i1] = excl + v0;
    if (t == 255) bbase[kNB] = incl;
}

// ---------- pass 3: scatter pairs; each (chunk,bucket) run is block-private ----------
__global__ void __launch_bounds__(512) gcn_scatter(const int* __restrict__ ei,
                                                   const int* __restrict__ bbase,
                                                   const int* __restrict__ reloff,
                                                   unsigned int* __restrict__ pairs,
                                                   const int* __restrict__ flags) {
    __shared__ int cur[kNB];
    int is64 = flags[1];
    int blk = blockIdx.x, t = threadIdx.x;
    for (int i = t; i < kNB; i += 512) cur[i] = bbase[i] + reloff[i * 256 + blk];
    __syncthreads();
    int e0 = blk * kCE, e1 = e0 + kCE;
    for (int e = e0 + t; e < e1; e += 512) {
        unsigned int d = (unsigned int)lde(ei, kE + e, is64);
        if (d < (unsigned int)kN) {
            unsigned int s = (unsigned int)lde(ei, e, is64);
            if (s >= (unsigned int)kN) s = 0;
            int p = atomicAdd(&cur[d >> 8], 1);
            pairs[p] = (s << 8) | (d & 255u);     // s < 2^17, dloc 8 bits
        }
    }
}

// ---------- layer-1: per-bucket LDS fp32 aggregation from pairs ----------
__global__ void __launch_bounds__(512) GCN_2190433321521_kernel(
        const unsigned int* __restrict__ pairs,
        const int* __restrict__ bbase,
        const uint4* __restrict__ xpack,
        float* __restrict__ agg) {
    __shared__ float agg_l[kBN][28];    // 28.7 KB
    int b = blockIdx.x;
    int base = b * kBN;
    int nn = min(kBN, kN - base);
    int tid = threadIdx.x;
    float* aflat = (float*)agg_l;
    for (int i = tid; i < kBN * 28; i += 512) aflat[i] = 0.f;
    __syncthreads();
    int p0 = bbase[b], p1 = bbase[b + 1];
    for (int i = p0 + tid; i < p1; i += 512) {
        unsigned int w = pairs[i];
        unsigned int s = w >> 8;
        int dloc = (int)(w & 255u);
        int sb = (s < (unsigned int)kNR) ? 0 : ((s < (unsigned int)(kNR + kNU)) ? 8 : 16);
        uint4 u = xpack[s];
        float2 q0 = bf2_to_f2(u.x), q1 = bf2_to_f2(u.y);
        float2 q2 = bf2_to_f2(u.z), q3 = bf2_to_f2(u.w);
        float* a = &agg_l[dloc][sb];
        atomicAdd(&a[0], q0.x); atomicAdd(&a[1], q0.y);
        atomicAdd(&a[2], q1.x); atomicAdd(&a[3], q1.y);
        atomicAdd(&a[4], q2.x); atomicAdd(&a[5], q2.y);
        atomicAdd(&a[6], q3.x); atomicAdd(&a[7], q3.y);
        atomicAdd(&agg_l[dloc][24 + (sb >> 3)], 1.f);
    }
    __syncthreads();
    for (int i = tid; i < nn * 32; i += 512) {
        int n = i >> 5, sl = i & 31;
        agg[(size_t)(base + n) * kAS + sl] = (sl < 27) ? agg_l[n][sl] : 0.f;
    }
}

// ---------- dense via MFMA: one wave per 16 nodes (verified R7) ----------
__global__ void __launch_bounds__(256) gcn_dense(const float* __restrict__ agg,
                                                 const unsigned short* __restrict__ fwT,
                                                 const void* __restrict__ W2,
                                                 unsigned short* __restrict__ hw,
                                                 const int* __restrict__ flags) {
    __shared__ __align__(16) unsigned short sfwT[kF][40];
    __shared__ __align__(16) unsigned short sw2T[48][136];
    __shared__ __align__(16) unsigned short hbuf[4][16][136];
    int isbf = flags[0];
    int tid = threadIdx.x;
    for (int i = tid; i < kF * 32; i += 256) sfwT[i >> 5][i & 31] = fwT[i];
    for (int i = tid; i < 48 * kF; i += 256) {
        int c = i >> 7, k = i & 127;
        sw2T[c][k] = (c < kC) ? f_to_bf(ldf(W2, k * kC + c, isbf)) : (unsigned short)0;
    }
    __syncthreads();
    int wid = tid >> 6, lane = tid & 63;
    int T = blockIdx.x * 4 + wid;
    if (T >= kN / 16) return;
    int n0 = T * 16;
    int m = lane & 15, q = lane >> 4;

    const float* ar = agg + (size_t)(n0 + m) * kAS + q * 8;
    bf16x8 a1;
    #pragma unroll
    for (int i = 0; i < 8; i++) a1[i] = (short)f_to_bf(ar[i]);

    f32x4 c1[8];
    #pragma unroll
    for (int t = 0; t < 8; t++) {
        bf16x8 bfr = *(const bf16x8*)&sfwT[16 * t + m][q * 8];
        f32x4 z = {0.f, 0.f, 0.f, 0.f};
        c1[t] = __builtin_amdgcn_mfma_f32_16x16x32_bf16(a1, bfr, z, 0, 0, 0);
    }
    #pragma unroll
    for (int t = 0; t < 8; t++) {
        #pragma unroll
        for (int r = 0; r < 4; r++)
            hbuf[wid][q * 4 + r][16 * t + m] = f_to_bf(fmaxf(c1[t][r], 0.f));
    }
    f32x4 c2[3];
    #pragma unroll
    for (int t = 0; t < 3; t++) { c2[t].x = 0.f; c2[t].y = 0.f; c2[t].z = 0.f; c2[t].w = 0.f; }
    #pragma unroll
    for (int s = 0; s < 4; s++) {
        bf16x8 a2 = *(const bf16x8*)&hbuf[wid][m][s * 32 + q * 8];
        #pragma unroll
        for (int t = 0; t < 3; t++) {
            bf16x8 b2 = *(const bf16x8*)&sw2T[16 * t + m][s * 32 + q * 8];
            c2[t] = __builtin_amdgcn_mfma_f32_16x16x32_bf16(a2, b2, c2[t], 0, 0, 0);
        }
    }
    #pragma unroll
    for (int t = 0; t < 3; t++) {
        int cls = 16 * t + m;
        if (cls < kC) {
            #pragma unroll
            for (int r = 0; r < 4; r++)
                hw[(size_t)(n0 + q * 4 + r) * kC + cls] = f_to_bf(c2[t][r]);
        }
    }
}

// ---------- layer-2: per-bucket LDS fp32 output accumulation from pairs ----------
__global__ void __launch_bounds__(512) gcn_out(const unsigned int* __restrict__ pairs,
                                               const int* __restrict__ bbase,
                                               const unsigned int* __restrict__ hw32,
                                               unsigned int* __restrict__ out,
                                               const int* __restrict__ flags) {
    __shared__ float ol[kBN * 40];      // 40 KB
    int isbf = flags[0];
    int b = blockIdx.x;
    int base = b * kBN;
    int nn = min(kBN, kN - base);
    int tid = threadIdx.x;
    for (int i = tid; i < kBN * 40; i += 512) ol[i] = 0.f;
    __syncthreads();
    int p0 = bbase[b], p1 = bbase[b + 1];
    int lane = tid & 63, wid = tid >> 6;
    int grp = lane / 20, c2 = lane % 20;
    if (grp < 3) {
        for (int i = p0 + wid * 3 + grp; i < p1; i += 24) {   // 8 waves x 3 edges
            unsigned int w = pairs[i];
            unsigned int s = w >> 8;
            int dloc = (int)(w & 255u);
            float2 f = bf2_to_f2(hw32[s * 20 + c2]);
            atomicAdd(&ol[dloc * 40 + 2 * c2],     f.x);
            atomicAdd(&ol[dloc * 40 + 2 * c2 + 1], f.y);
        }
    }
    __syncthreads();
    if (isbf) {
        for (int i = tid; i < nn * 20; i += 512) {
            int n = i / 20, c = i % 20;
            out[(size_t)(base + n) * 20 + c] = pack_bf2(ol[n * 40 + 2 * c], ol[n * 40 + 2 * c + 1]);
        }
    } else {
        float* of = (float*)out;
        for (int i = tid; i < nn * 40; i += 512) {
            int n = i / 40, c = i % 40;
            of[(size_t)(base + n) * 40 + c] = ol[n * 40 + c];
        }
    }
}

extern "C" void kernel_launch(void* const* d_in, const int* in_sizes, int n_in,
                              void* d_out, int out_size, void* d_ws, size_t ws_size,
                              hipStream_t stream) {
    const void* xr = d_in[0];
    const void* xu = d_in[1];
    const void* xp = d_in[2];
    const int*  ei = (const int*)d_in[3];
    const void* Wr = d_in[4];
    const void* br = d_in[5];
    const void* Wu = d_in[6];
    const void* bu = d_in[7];
    const void* Wp = d_in[8];
    const void* bp = d_in[9];
    const void* W1 = d_in[10];
    const void* W2 = d_in[11];
    (void)in_sizes; (void)n_in; (void)out_size; (void)ws_size;

    char* ws = (char*)d_ws;
    size_t off = 0;
    auto alloc = [&](size_t bytes) -> void* {
        void* p = (void*)(ws + off);
        off = (off + bytes + 255) & ~(size_t)255;
        return p;
    };
    int*            flags  = (int*)           alloc(256);
    int*            cmat   = (int*)           alloc((size_t)kCH * 400 * 4);   // 400 KB
    int*            reloff = (int*)           alloc((size_t)kNB * 256 * 4);   // 400 KB
    int*            btot   = (int*)           alloc((size_t)kNB * 4);
    int*            bbase  = (int*)           alloc((size_t)(kNB + 1) * 4);
    unsigned short* fwT    = (unsigned short*)alloc(kF * 32 * 2);             // 8 KB
    uint4*          xpack  = (uint4*)         alloc((size_t)kN * 16);         // 1.6 MB
    unsigned int*   pairs  = (unsigned int*)  alloc((size_t)kE * 4);          // 6.4 MB
    unsigned short* hwb    = (unsigned short*)alloc((size_t)kN * kC * 2);     // 8 MB
    float*          agg    = (float*)         alloc((size_t)kN * kAS * 4);    // 12.8 MB

    gcn_sniff<<<1, 64, 0, stream>>>((const unsigned int*)W1, ei, flags);
    gcn_fuse<<<1, 128, 0, stream>>>(Wr, br, Wu, bu, Wp, bp, W1, fwT, flags);
    gcn_pack<<<(kN + 255) / 256, 256, 0, stream>>>(xr, xu, xp, xpack, flags);
    gcn_count<<<kCH, 512, 0, stream>>>(ei, cmat, flags);
    gcn_scanB1<<<kNB, 256, 0, stream>>>(cmat, reloff, btot);
    gcn_scanB2<<<1, 256, 0, stream>>>(btot, bbase);
    gcn_scatter<<<kCH, 512, 0, stream>>>(ei, bbase, reloff, pairs, flags);
    GCN_2190433321521_kernel<<<kNB, 512, 0, stream>>>(pairs, bbase, xpack, agg);
    gcn_dense<<<(kN / 16 + 3) / 4, 256, 0, stream>>>(agg, fwT, W2, hwb, flags);
    gcn_out<<<kNB, 512, 0, stream>>>(pairs, bbase, (const unsigned int*)hwb,
                                     (unsigned int*)d_out, flags);
}

// Round 10
// 332.846 us; speedup vs baseline: 2.7996x; 2.1188x over previous
//
#include <hip/hip_runtime.h>

constexpr int kNR = 40000;
constexpr int kNU = 30000;
constexpr int kNP = 30000;
constexpr int kN  = 100000;          // total nodes
constexpr int kE  = 1600000;         // edges
constexpr int kF  = 128;             // feature/hidden dim
constexpr int kC  = 40;              // classes
constexpr int kAS = 32;              // agg row stride (27 used; 128B rows)
constexpr int kBN = 256;             // nodes per bucket
constexpr int kNB = (kN + kBN - 1) / kBN;   // 391 buckets
constexpr int kCH = 256;             // edge chunks
constexpr int kCE = kE / kCH;        // 6250 edges per chunk (exact)
constexpr int kColCap = 6144;        // LDS col staging capacity (avg bucket 4096)

typedef __attribute__((ext_vector_type(8))) short bf16x8;   // 4 VGPRs: MFMA A/B frag
typedef __attribute__((ext_vector_type(4))) float f32x4;    // MFMA C/D frag

// ---------- bf16 helpers (storage-only; math in fp32) ----------
__device__ __forceinline__ float bf_to_f(unsigned short h) {
    union { unsigned int i; float f; } u; u.i = ((unsigned int)h) << 16; return u.f;
}
__device__ __forceinline__ unsigned short f_to_bf(float f) {
    union { unsigned int i; float f; } u; u.f = f;
    unsigned int r = u.i + 0x7FFFu + ((u.i >> 16) & 1u);   // round-nearest-even
    return (unsigned short)(r >> 16);
}
__device__ __forceinline__ float2 bf2_to_f2(unsigned int p) {
    union { unsigned int i; float f; } lo, hi;
    lo.i = (p & 0xFFFFu) << 16;
    hi.i = p & 0xFFFF0000u;
    return make_float2(lo.f, hi.f);
}
__device__ __forceinline__ unsigned int pack_bf2(float a, float b) {
    return (unsigned int)f_to_bf(a) | ((unsigned int)f_to_bf(b) << 16);
}
__device__ __forceinline__ float ldf(const void* p, int i, int isbf) {
    return isbf ? bf_to_f(((const unsigned short*)p)[i]) : ((const float*)p)[i];
}
__device__ __forceinline__ int lde(const int* p, int i, int is64) {
    return is64 ? p[2 * i] : p[i];
}

// ---------- sniff dtypes -> flags[0]=isbf, flags[1]=is64 ----------
__global__ void gcn_sniff(const unsigned int* __restrict__ w1w,
                          const int* __restrict__ eiw, int* __restrict__ flags) {
    if (blockIdx.x != 0 || threadIdx.x != 0) return;
    int plaus = 0;
    for (int k = 0; k < 64; k++) {
        unsigned int ax = w1w[k] & 0x7FFFu;
        plaus += (ax == 0u) || (ax > 0x2000u && ax < 0x4000u);
    }
    flags[0] = (plaus >= 48) ? 1 : 0;
    int nz = 0;
    for (int k = 0; k < 64; k++) nz |= eiw[2 * k + 1];
    flags[1] = (nz == 0) ? 1 : 0;
}

// ---------- fused weights, TRANSPOSED bf16: fwT[feat(128)][slot(32)] ----------
__global__ void gcn_fuse(const void* __restrict__ Wr, const void* __restrict__ br,
                         const void* __restrict__ Wu, const void* __restrict__ bu,
                         const void* __restrict__ Wp, const void* __restrict__ bp,
                         const void* __restrict__ W1, unsigned short* __restrict__ fwT,
                         const int* __restrict__ flags) {
    __shared__ float sw[21 * kF];
    int isbf = flags[0];
    int t = threadIdx.x;             // 128 threads
    for (int i = t; i < 21 * kF; i += 128) {
        int r = i >> 7, c = i & 127;
        float v;
        if (r < 5)        v = ldf(Wr, r * kF + c, isbf);
        else if (r < 12)  v = ldf(Wu, (r - 5) * kF + c, isbf);
        else if (r < 18)  v = ldf(Wp, (r - 12) * kF + c, isbf);
        else if (r == 18) v = ldf(br, c, isbf);
        else if (r == 19) v = ldf(bu, c, isbf);
        else              v = ldf(bp, c, isbf);
        sw[i] = v;
    }
    __syncthreads();
    int j = t;
    float acc[21];
    #pragma unroll
    for (int r = 0; r < 21; r++) acc[r] = 0.f;
    for (int k = 0; k < kF; k++) {
        float w1 = ldf(W1, k * kF + j, isbf);
        #pragma unroll
        for (int r = 0; r < 21; r++) acc[r] += sw[r * kF + k] * w1;
    }
    unsigned short row[32];
    #pragma unroll
    for (int s = 0; s < 32; s++) row[s] = 0;
    #pragma unroll
    for (int i = 0; i < 5; i++) row[0  + i] = f_to_bf(acc[i]);
    #pragma unroll
    for (int i = 0; i < 7; i++) row[8  + i] = f_to_bf(acc[5 + i]);
    #pragma unroll
    for (int i = 0; i < 6; i++) row[16 + i] = f_to_bf(acc[12 + i]);
    row[24] = f_to_bf(acc[18]);  row[25] = f_to_bf(acc[19]);  row[26] = f_to_bf(acc[20]);
    #pragma unroll
    for (int s = 0; s < 32; s++) fwT[j * 32 + s] = row[s];
}

// ---------- pack raw features: xpack[n] = uint4 of 8 bf16 (zero-padded) ----------
__global__ void __launch_bounds__(256) gcn_pack(const void* __restrict__ xr,
                                                const void* __restrict__ xu,
                                                const void* __restrict__ xp,
                                                uint4* __restrict__ xpack,
                                                const int* __restrict__ flags) {
    int isbf = flags[0];
    int n = blockIdx.x * 256 + threadIdx.x;
    if (n >= kN) return;
    const void* base; int roff, d;
    if (n < kNR)            { base = xr; roff = n * 5;               d = 5; }
    else if (n < kNR + kNU) { base = xu; roff = (n - kNR) * 7;       d = 7; }
    else                    { base = xp; roff = (n - kNR - kNU) * 6; d = 6; }
    float f[8];
    #pragma unroll
    for (int i = 0; i < 8; i++) f[i] = (i < d) ? ldf(base, roff + i, isbf) : 0.f;
    uint4 u;
    u.x = pack_bf2(f[0], f[1]);  u.y = pack_bf2(f[2], f[3]);
    u.z = pack_bf2(f[4], f[5]);  u.w = pack_bf2(f[6], f[7]);
    xpack[n] = u;
}

// ---------- multisplit pass 1: per-chunk bucket counts -> cmat[chunk][400] ----------
__global__ void __launch_bounds__(512) gcn_count(const int* __restrict__ ei,
                                                 int* __restrict__ cmat,
                                                 const int* __restrict__ flags) {
    __shared__ int cl[400];
    int is64 = flags[1];
    int blk = blockIdx.x, t = threadIdx.x;
    for (int i = t; i < 400; i += 512) cl[i] = 0;
    __syncthreads();
    int e0 = blk * kCE, e1 = e0 + kCE;
    for (int e = e0 + t; e < e1; e += 512) {
        unsigned int d = (unsigned int)lde(ei, kE + e, is64);
        if (d < (unsigned int)kN) atomicAdd(&cl[d >> 8], 1);
    }
    __syncthreads();
    for (int i = t; i < 400; i += 512) cmat[blk * 400 + i] = cl[i];   // coalesced
}

// ---------- pass 2a: per-bucket scan over chunks -> reloff[b][chunk], btot[b] ----------
__global__ void gcn_scanB1(const int* __restrict__ cmat, int* __restrict__ reloff,
                           int* __restrict__ btot) {
    __shared__ int lds[256];
    int b = blockIdx.x, t = threadIdx.x;
    int v = cmat[t * 400 + b];
    int incl = v; lds[t] = incl; __syncthreads();
    for (int o = 1; o < 256; o <<= 1) {
        int y = (t >= o) ? lds[t - o] : 0;
        __syncthreads();
        incl += y; lds[t] = incl;
        __syncthreads();
    }
    reloff[b * 256 + t] = incl - v;
    if (t == 255) btot[b] = incl;
}

// ---------- pass 2b: scan 391 bucket totals -> bbase[0..391] ----------
__global__ void gcn_scanB2(const int* __restrict__ btot, int* __restrict__ bbase) {
    __shared__ int lds[256];
    int t = threadIdx.x;
    int i0 = 2 * t, i1 = 2 * t + 1;
    int v0 = (i0 < kNB) ? btot[i0] : 0;
    int v1 = (i1 < kNB) ? btot[i1] : 0;
    int s = v0 + v1;
    int incl = s; lds[t] = incl; __syncthreads();
    for (int o = 1; o < 256; o <<= 1) {
        int y = (t >= o) ? lds[t - o] : 0;
        __syncthreads();
        incl += y; lds[t] = incl;
        __syncthreads();
    }
    int excl = incl - s;
    if (i0 < kNB) bbase[i0] = excl;
    if (i1 < kNB) bbase[i1] = excl + v0;
    if (t == 255) bbase[kNB] = incl;
}

// ---------- pass 3: scatter pairs; each (chunk,bucket) run is block-private ----------
__global__ void __launch_bounds__(512) gcn_scatter(const int* __restrict__ ei,
                                                   const int* __restrict__ bbase,
                                                   const int* __restrict__ reloff,
                                                   unsigned int* __restrict__ pairs,
                                                   const int* __restrict__ flags) {
    __shared__ int cur[kNB];
    int is64 = flags[1];
    int blk = blockIdx.x, t = threadIdx.x;
    for (int i = t; i < kNB; i += 512) cur[i] = bbase[i] + reloff[i * 256 + blk];
    __syncthreads();
    int e0 = blk * kCE, e1 = e0 + kCE;
    for (int e = e0 + t; e < e1; e += 512) {
        unsigned int d = (unsigned int)lde(ei, kE + e, is64);
        if (d < (unsigned int)kN) {
            unsigned int s = (unsigned int)lde(ei, e, is64);
            if (s >= (unsigned int)kN) s = 0;
            int p = atomicAdd(&cur[d >> 8], 1);
            pairs[p] = (s << 8) | (d & 255u);     // s < 2^17, dloc 8 bits
        }
    }
}

// ---------- bucket kernel: node-CSR build (rp,col) + layer-1 LDS fp32 aggregation ----------
__global__ void __launch_bounds__(512) GCN_2190433321521_kernel(
        const unsigned int* __restrict__ pairs,
        const int* __restrict__ bbase,
        const uint4* __restrict__ xpack,
        int* __restrict__ rp,
        int* __restrict__ col,
        float* __restrict__ agg) {
    __shared__ float agg_l[kBN][28];    // 28.7 KB
    __shared__ int   cnt_l[kBN];        // counts -> cursors (global coords)
    __shared__ int   scan_l[kBN];
    __shared__ int   col_l[kColCap];    // 24 KB staging
    int b = blockIdx.x;
    int base = b * kBN;
    int nn = min(kBN, kN - base);
    int tid = threadIdx.x;
    float* aflat = (float*)agg_l;
    for (int i = tid; i < kBN * 28; i += 512) aflat[i] = 0.f;
    for (int i = tid; i < kBN; i += 512) cnt_l[i] = 0;
    __syncthreads();
    int p0 = bbase[b], p1 = bbase[b + 1];
    int m = p1 - p0;

    // pass 1: per-node histogram of this bucket's pairs
    for (int i = p0 + tid; i < p1; i += 512) atomicAdd(&cnt_l[pairs[i] & 255u], 1);
    __syncthreads();
    // LDS scan over 256 node-counts (threads >=256 only hit barriers)
    int v = (tid < kBN) ? cnt_l[tid] : 0;
    int incl = v;
    if (tid < kBN) scan_l[tid] = incl;
    __syncthreads();
    for (int o = 1; o < kBN; o <<= 1) {
        int y = (tid < kBN && tid >= o) ? scan_l[tid - o] : 0;
        __syncthreads();
        if (tid < kBN) { incl += y; scan_l[tid] = incl; }
        __syncthreads();
    }
    if (tid < kBN) {
        int cursor = p0 + incl - v;            // global position of node's run
        cnt_l[tid] = cursor;
        if (tid < nn) rp[base + tid] = cursor;
    }
    if (b == kNB - 1 && tid == 0) rp[kN] = p1;
    __syncthreads();

    // pass 2: col build + agg accumulate
    bool fits = (m <= kColCap);
    for (int i = p0 + tid; i < p1; i += 512) {
        unsigned int w = pairs[i];
        unsigned int s = w >> 8;
        int dloc = (int)(w & 255u);
        int pos = atomicAdd(&cnt_l[dloc], 1);
        if (fits) col_l[pos - p0] = (int)s;
        else      col[pos] = (int)s;           // rare fallback: 24KB-window scatter
        int sb = (s < (unsigned int)kNR) ? 0 : ((s < (unsigned int)(kNR + kNU)) ? 8 : 16);
        uint4 u = xpack[s];
        float2 q0 = bf2_to_f2(u.x), q1 = bf2_to_f2(u.y);
        float2 q2 = bf2_to_f2(u.z), q3 = bf2_to_f2(u.w);
        float* a = &agg_l[dloc][sb];
        atomicAdd(&a[0], q0.x); atomicAdd(&a[1], q0.y);
        atomicAdd(&a[2], q1.x); atomicAdd(&a[3], q1.y);
        atomicAdd(&a[4], q2.x); atomicAdd(&a[5], q2.y);
        atomicAdd(&a[6], q3.x); atomicAdd(&a[7], q3.y);
        atomicAdd(&agg_l[dloc][24 + (sb >> 3)], 1.f);
    }
    __syncthreads();
    if (fits) {
        for (int i = tid; i < m; i += 512) col[p0 + i] = col_l[i];   // coalesced
    }
    for (int i = tid; i < nn * 32; i += 512) {
        int n = i >> 5, sl = i & 31;
        agg[(size_t)(base + n) * kAS + sl] = (sl < 27) ? agg_l[n][sl] : 0.f;
    }
}

// ---------- dense via MFMA: one wave per 16 nodes (verified R7) ----------
__global__ void __launch_bounds__(256) gcn_dense(const float* __restrict__ agg,
                                                 const unsigned short* __restrict__ fwT,
                                                 const void* __restrict__ W2,
                                                 unsigned short* __restrict__ hw,
                                                 const int* __restrict__ flags) {
    __shared__ __align__(16) unsigned short sfwT[kF][40];
    __shared__ __align__(16) unsigned short sw2T[48][136];
    __shared__ __align__(16) unsigned short hbuf[4][16][136];
    int isbf = flags[0];
    int tid = threadIdx.x;
    for (int i = tid; i < kF * 32; i += 256) sfwT[i >> 5][i & 31] = fwT[i];
    for (int i = tid; i < 48 * kF; i += 256) {
        int c = i >> 7, k = i & 127;
        sw2T[c][k] = (c < kC) ? f_to_bf(ldf(W2, k * kC + c, isbf)) : (unsigned short)0;
    }
    __syncthreads();
    int wid = tid >> 6, lane = tid & 63;
    int T = blockIdx.x * 4 + wid;
    if (T >= kN / 16) return;
    int n0 = T * 16;
    int m = lane & 15, q = lane >> 4;

    const float* ar = agg + (size_t)(n0 + m) * kAS + q * 8;
    bf16x8 a1;
    #pragma unroll
    for (int i = 0; i < 8; i++) a1[i] = (short)f_to_bf(ar[i]);

    f32x4 c1[8];
    #pragma unroll
    for (int t = 0; t < 8; t++) {
        bf16x8 bfr = *(const bf16x8*)&sfwT[16 * t + m][q * 8];
        f32x4 z = {0.f, 0.f, 0.f, 0.f};
        c1[t] = __builtin_amdgcn_mfma_f32_16x16x32_bf16(a1, bfr, z, 0, 0, 0);
    }
    #pragma unroll
    for (int t = 0; t < 8; t++) {
        #pragma unroll
        for (int r = 0; r < 4; r++)
            hbuf[wid][q * 4 + r][16 * t + m] = f_to_bf(fmaxf(c1[t][r], 0.f));
    }
    f32x4 c2[3];
    #pragma unroll
    for (int t = 0; t < 3; t++) { c2[t].x = 0.f; c2[t].y = 0.f; c2[t].z = 0.f; c2[t].w = 0.f; }
    #pragma unroll
    for (int s = 0; s < 4; s++) {
        bf16x8 a2 = *(const bf16x8*)&hbuf[wid][m][s * 32 + q * 8];
        #pragma unroll
        for (int t = 0; t < 3; t++) {
            bf16x8 b2 = *(const bf16x8*)&sw2T[16 * t + m][s * 32 + q * 8];
            c2[t] = __builtin_amdgcn_mfma_f32_16x16x32_bf16(a2, b2, c2[t], 0, 0, 0);
        }
    }
    #pragma unroll
    for (int t = 0; t < 3; t++) {
        int cls = 16 * t + m;
        if (cls < kC) {
            #pragma unroll
            for (int r = 0; r < 4; r++)
                hw[(size_t)(n0 + q * 4 + r) * kC + cls] = f_to_bf(c2[t][r]);
        }
    }
}

// ---------- layer-2 gather: wave-per-node, 3 edge-groups x 20 class-lanes (R7-verified) ----------
__global__ void __launch_bounds__(256) gcn_gather2(const unsigned int* __restrict__ hw32,
                                                   const int* __restrict__ rp,
                                                   const int* __restrict__ col,
                                                   unsigned int* __restrict__ out,
                                                   const int* __restrict__ flags) {
    int isbf = flags[0];
    int w = (blockIdx.x * 256 + threadIdx.x) >> 6;
    if (w >= kN) return;
    int lane = threadIdx.x & 63;
    int grp = lane / 20;
    int c2  = lane % 20;
    int beg = rp[w], end = rp[w + 1];
    float ax = 0.f, ay = 0.f;
    if (grp < 3) {
        int e = beg + grp;
        for (; e + 3 < end; e += 6) {
            float2 f0 = bf2_to_f2(hw32[col[e]     * 20 + c2]);
            float2 f1 = bf2_to_f2(hw32[col[e + 3] * 20 + c2]);
            ax += f0.x + f1.x;  ay += f0.y + f1.y;
        }
        if (e < end) {
            float2 f = bf2_to_f2(hw32[col[e] * 20 + c2]);
            ax += f.x; ay += f.y;
        }
    }
    ax += __shfl(ax, lane + 20, 64) + __shfl(ax, lane + 40, 64);
    ay += __shfl(ay, lane + 20, 64) + __shfl(ay, lane + 40, 64);
    if (lane < 20) {
        if (isbf) {
            out[w * 20 + lane] = pack_bf2(ax, ay);
        } else {
            float* of = (float*)out;
            of[w * 40 + 2*lane]     = ax;
            of[w * 40 + 2*lane + 1] = ay;
        }
    }
}

extern "C" void kernel_launch(void* const* d_in, const int* in_sizes, int n_in,
                              void* d_out, int out_size, void* d_ws, size_t ws_size,
                              hipStream_t stream) {
    const void* xr = d_in[0];
    const void* xu = d_in[1];
    const void* xp = d_in[2];
    const int*  ei = (const int*)d_in[3];
    const void* Wr = d_in[4];
    const void* br = d_in[5];
    const void* Wu = d_in[6];
    const void* bu = d_in[7];
    const void* Wp = d_in[8];
    const void* bp = d_in[9];
    const void* W1 = d_in[10];
    const void* W2 = d_in[11];
    (void)in_sizes; (void)n_in; (void)out_size; (void)ws_size;

    char* ws = (char*)d_ws;
    size_t off = 0;
    auto alloc = [&](size_t bytes) -> void* {
        void* p = (void*)(ws + off);
        off = (off + bytes + 255) & ~(size_t)255;
        return p;
    };
    int*            flags  = (int*)           alloc(256);
    int*            cmat   = (int*)           alloc((size_t)kCH * 400 * 4);   // 400 KB
    int*            reloff = (int*)           alloc((size_t)kNB * 256 * 4);   // 400 KB
    int*            btot   = (int*)           alloc((size_t)kNB * 4);
    int*            bbase  = (int*)           alloc((size_t)(kNB + 1) * 4);
    int*            rp     = (int*)           alloc((size_t)(kN + 1) * 4);
    unsigned short* fwT    = (unsigned short*)alloc(kF * 32 * 2);             // 8 KB
    uint4*          xpack  = (uint4*)         alloc((size_t)kN * 16);         // 1.6 MB
    unsigned int*   pairs  = (unsigned int*)  alloc((size_t)kE * 4);          // 6.4 MB
    int*            col    = (int*)           alloc((size_t)kE * 4);          // 6.4 MB
    unsigned short* hwb    = (unsigned short*)alloc((size_t)kN * kC * 2);     // 8 MB
    float*          agg    = (float*)         alloc((size_t)kN * kAS * 4);    // 12.8 MB

    gcn_sniff<<<1, 64, 0, stream>>>((const unsigned int*)W1, ei, flags);
    gcn_fuse<<<1, 128, 0, stream>>>(Wr, br, Wu, bu, Wp, bp, W1, fwT, flags);
    gcn_pack<<<(kN + 255) / 256, 256, 0, stream>>>(xr, xu, xp, xpack, flags);
    gcn_count<<<kCH, 512, 0, stream>>>(ei, cmat, flags);
    gcn_scanB1<<<kNB, 256, 0, stream>>>(cmat, reloff, btot);
    gcn_scanB2<<<1, 256, 0, stream>>>(btot, bbase);
    gcn_scatter<<<kCH, 512, 0, stream>>>(ei, bbase, reloff, pairs, flags);
    GCN_2190433321521_kernel<<<kNB, 512, 0, stream>>>(pairs, bbase, xpack, rp, col, agg);
    gcn_dense<<<(kN / 16 + 3) / 4, 256, 0, stream>>>(agg, fwT, W2, hwb, flags);
    gcn_gather2<<<(kN * 64 + 255) / 256, 256, 0, stream>>>((const unsigned int*)hwb, rp, col,
                                                           (unsigned int*)d_out, flags);
}

// Round 11
// 327.821 us; speedup vs baseline: 2.8426x; 1.0153x over previous
//
#include <hip/hip_runtime.h>

constexpr int kNR = 40000;
constexpr int kNU = 30000;
constexpr int kNP = 30000;
constexpr int kN  = 100000;          // total nodes
constexpr int kE  = 1600000;         // edges
constexpr int kF  = 128;             // feature/hidden dim
constexpr int kC  = 40;              // classes
constexpr int kAS = 32;              // agg row stride (27 used; 128B rows)
constexpr int kBN = 64;              // nodes per bucket (R10: 256 -> 64 for occupancy)
constexpr int kNB = (kN + kBN - 1) / kBN;   // 1563 buckets
constexpr int kNBp = 1600;           // padded bucket-count stride
constexpr int kCH = 256;             // edge chunks
constexpr int kCE = kE / kCH;        // 6250 edges per chunk (exact)
constexpr int kColCap = 2048;        // LDS col staging capacity (avg bucket 1024)

typedef __attribute__((ext_vector_type(8))) short bf16x8;   // 4 VGPRs: MFMA A/B frag
typedef __attribute__((ext_vector_type(4))) float f32x4;    // MFMA C/D frag

// ---------- bf16 helpers (storage-only; math in fp32) ----------
__device__ __forceinline__ float bf_to_f(unsigned short h) {
    union { unsigned int i; float f; } u; u.i = ((unsigned int)h) << 16; return u.f;
}
__device__ __forceinline__ unsigned short f_to_bf(float f) {
    union { unsigned int i; float f; } u; u.f = f;
    unsigned int r = u.i + 0x7FFFu + ((u.i >> 16) & 1u);   // round-nearest-even
    return (unsigned short)(r >> 16);
}
__device__ __forceinline__ float2 bf2_to_f2(unsigned int p) {
    union { unsigned int i; float f; } lo, hi;
    lo.i = (p & 0xFFFFu) << 16;
    hi.i = p & 0xFFFF0000u;
    return make_float2(lo.f, hi.f);
}
__device__ __forceinline__ unsigned int pack_bf2(float a, float b) {
    return (unsigned int)f_to_bf(a) | ((unsigned int)f_to_bf(b) << 16);
}
__device__ __forceinline__ float ldf(const void* p, int i, int isbf) {
    return isbf ? bf_to_f(((const unsigned short*)p)[i]) : ((const float*)p)[i];
}
__device__ __forceinline__ int lde(const int* p, int i, int is64) {
    return is64 ? p[2 * i] : p[i];
}

// ---------- sniff dtypes -> flags[0]=isbf, flags[1]=is64 ----------
__global__ void gcn_sniff(const unsigned int* __restrict__ w1w,
                          const int* __restrict__ eiw, int* __restrict__ flags) {
    if (blockIdx.x != 0 || threadIdx.x != 0) return;
    int plaus = 0;
    for (int k = 0; k < 64; k++) {
        unsigned int ax = w1w[k] & 0x7FFFu;
        plaus += (ax == 0u) || (ax > 0x2000u && ax < 0x4000u);
    }
    flags[0] = (plaus >= 48) ? 1 : 0;
    int nz = 0;
    for (int k = 0; k < 64; k++) nz |= eiw[2 * k + 1];
    flags[1] = (nz == 0) ? 1 : 0;
}

// ---------- fused weights, TRANSPOSED bf16: fwT[feat(128)][slot(32)] ----------
__global__ void gcn_fuse(const void* __restrict__ Wr, const void* __restrict__ br,
                         const void* __restrict__ Wu, const void* __restrict__ bu,
                         const void* __restrict__ Wp, const void* __restrict__ bp,
                         const void* __restrict__ W1, unsigned short* __restrict__ fwT,
                         const int* __restrict__ flags) {
    __shared__ float sw[21 * kF];
    int isbf = flags[0];
    int t = threadIdx.x;             // 128 threads
    for (int i = t; i < 21 * kF; i += 128) {
        int r = i >> 7, c = i & 127;
        float v;
        if (r < 5)        v = ldf(Wr, r * kF + c, isbf);
        else if (r < 12)  v = ldf(Wu, (r - 5) * kF + c, isbf);
        else if (r < 18)  v = ldf(Wp, (r - 12) * kF + c, isbf);
        else if (r == 18) v = ldf(br, c, isbf);
        else if (r == 19) v = ldf(bu, c, isbf);
        else              v = ldf(bp, c, isbf);
        sw[i] = v;
    }
    __syncthreads();
    int j = t;
    float acc[21];
    #pragma unroll
    for (int r = 0; r < 21; r++) acc[r] = 0.f;
    for (int k = 0; k < kF; k++) {
        float w1 = ldf(W1, k * kF + j, isbf);
        #pragma unroll
        for (int r = 0; r < 21; r++) acc[r] += sw[r * kF + k] * w1;
    }
    unsigned short row[32];
    #pragma unroll
    for (int s = 0; s < 32; s++) row[s] = 0;
    #pragma unroll
    for (int i = 0; i < 5; i++) row[0  + i] = f_to_bf(acc[i]);
    #pragma unroll
    for (int i = 0; i < 7; i++) row[8  + i] = f_to_bf(acc[5 + i]);
    #pragma unroll
    for (int i = 0; i < 6; i++) row[16 + i] = f_to_bf(acc[12 + i]);
    row[24] = f_to_bf(acc[18]);  row[25] = f_to_bf(acc[19]);  row[26] = f_to_bf(acc[20]);
    #pragma unroll
    for (int s = 0; s < 32; s++) fwT[j * 32 + s] = row[s];
}

// ---------- pack raw features: xpack[n] = uint4 of 8 bf16 (zero-padded) ----------
__global__ void __launch_bounds__(256) gcn_pack(const void* __restrict__ xr,
                                                const void* __restrict__ xu,
                                                const void* __restrict__ xp,
                                                uint4* __restrict__ xpack,
                                                const int* __restrict__ flags) {
    int isbf = flags[0];
    int n = blockIdx.x * 256 + threadIdx.x;
    if (n >= kN) return;
    const void* base; int roff, d;
    if (n < kNR)            { base = xr; roff = n * 5;               d = 5; }
    else if (n < kNR + kNU) { base = xu; roff = (n - kNR) * 7;       d = 7; }
    else                    { base = xp; roff = (n - kNR - kNU) * 6; d = 6; }
    float f[8];
    #pragma unroll
    for (int i = 0; i < 8; i++) f[i] = (i < d) ? ldf(base, roff + i, isbf) : 0.f;
    uint4 u;
    u.x = pack_bf2(f[0], f[1]);  u.y = pack_bf2(f[2], f[3]);
    u.z = pack_bf2(f[4], f[5]);  u.w = pack_bf2(f[6], f[7]);
    xpack[n] = u;
}

// ---------- multisplit pass 1: per-chunk bucket counts -> cmat[chunk][kNBp] ----------
__global__ void __launch_bounds__(512) gcn_count(const int* __restrict__ ei,
                                                 int* __restrict__ cmat,
                                                 const int* __restrict__ flags) {
    __shared__ int cl[kNBp];
    int is64 = flags[1];
    int blk = blockIdx.x, t = threadIdx.x;
    for (int i = t; i < kNBp; i += 512) cl[i] = 0;
    __syncthreads();
    int e0 = blk * kCE, e1 = e0 + kCE;
    for (int e = e0 + t; e < e1; e += 512) {
        unsigned int d = (unsigned int)lde(ei, kE + e, is64);
        if (d < (unsigned int)kN) atomicAdd(&cl[d >> 6], 1);
    }
    __syncthreads();
    for (int i = t; i < kNBp; i += 512) cmat[blk * kNBp + i] = cl[i];   // coalesced
}

// ---------- pass 2a: per-bucket scan over chunks -> reloff[b][chunk], btot[b] ----------
__global__ void gcn_scanB1(const int* __restrict__ cmat, int* __restrict__ reloff,
                           int* __restrict__ btot) {
    __shared__ int lds[256];
    int b = blockIdx.x, t = threadIdx.x;
    int v = cmat[t * kNBp + b];
    int incl = v; lds[t] = incl; __syncthreads();
    for (int o = 1; o < 256; o <<= 1) {
        int y = (t >= o) ? lds[t - o] : 0;
        __syncthreads();
        incl += y; lds[t] = incl;
        __syncthreads();
    }
    reloff[b * 256 + t] = incl - v;
    if (t == 255) btot[b] = incl;
}

// ---------- pass 2b: scan 1563 bucket totals -> bbase[0..kNB] ----------
__global__ void gcn_scanB2(const int* __restrict__ btot, int* __restrict__ bbase) {
    __shared__ int lds[512];
    int t = threadIdx.x;
    int v[4]; int s = 0;
    #pragma unroll
    for (int j = 0; j < 4; j++) {
        int i = 4 * t + j;
        v[j] = (i < kNB) ? btot[i] : 0;
        s += v[j];
    }
    int incl = s; lds[t] = incl; __syncthreads();
    for (int o = 1; o < 512; o <<= 1) {
        int y = (t >= o) ? lds[t - o] : 0;
        __syncthreads();
        incl += y; lds[t] = incl;
        __syncthreads();
    }
    int excl = incl - s;
    #pragma unroll
    for (int j = 0; j < 4; j++) {
        int i = 4 * t + j;
        if (i < kNB) { bbase[i] = excl; excl += v[j]; }
    }
    if (t == 511) bbase[kNB] = incl;
}

// ---------- pass 3: scatter pairs; each (chunk,bucket) run is block-private ----------
__global__ void __launch_bounds__(512) gcn_scatter(const int* __restrict__ ei,
                                                   const int* __restrict__ bbase,
                                                   const int* __restrict__ reloff,
                                                   unsigned int* __restrict__ pairs,
                                                   const int* __restrict__ flags) {
    __shared__ int cur[kNB];
    int is64 = flags[1];
    int blk = blockIdx.x, t = threadIdx.x;
    for (int i = t; i < kNB; i += 512) cur[i] = bbase[i] + reloff[i * 256 + blk];
    __syncthreads();
    int e0 = blk * kCE, e1 = e0 + kCE;
    for (int e = e0 + t; e < e1; e += 512) {
        unsigned int d = (unsigned int)lde(ei, kE + e, is64);
        if (d < (unsigned int)kN) {
            unsigned int s = (unsigned int)lde(ei, e, is64);
            if (s >= (unsigned int)kN) s = 0;
            int p = atomicAdd(&cur[d >> 6], 1);
            pairs[p] = (s << 6) | (d & 63u);      // s < 2^17, dloc 6 bits
        }
    }
}

// ---------- bucket kernel: node-CSR build (rp,col) + layer-1 LDS fp32 aggregation ----------
// 1563 blocks x 256 thr, ~16KB LDS -> ~6-8 blocks/CU (R10: 391 blocks, 55KB, 25% occ).
__global__ void __launch_bounds__(256) GCN_2190433321521_kernel(
        const unsigned int* __restrict__ pairs,
        const int* __restrict__ bbase,
        const uint4* __restrict__ xpack,
        int* __restrict__ rp,
        int* __restrict__ col,
        float* __restrict__ agg) {
    __shared__ float agg_l[kBN][29];    // 7.4 KB; stride 29 breaks mod-32 bank aliasing
    __shared__ int   cnt_l[kBN];
    __shared__ int   scan_l[kBN];
    __shared__ int   col_l[kColCap];    // 8 KB staging
    int b = blockIdx.x;
    int base = b * kBN;
    int nn = min(kBN, kN - base);
    int tid = threadIdx.x;
    float* aflat = (float*)agg_l;
    for (int i = tid; i < kBN * 29; i += 256) aflat[i] = 0.f;
    if (tid < kBN) cnt_l[tid] = 0;
    __syncthreads();
    int p0 = bbase[b], p1 = bbase[b + 1];
    int m = p1 - p0;

    // pass 1: per-node histogram of this bucket's pairs
    for (int i = p0 + tid; i < p1; i += 256) atomicAdd(&cnt_l[pairs[i] & 63u], 1);
    __syncthreads();
    // LDS scan over 64 node-counts
    int v = (tid < kBN) ? cnt_l[tid] : 0;
    int incl = v;
    if (tid < kBN) scan_l[tid] = incl;
    __syncthreads();
    for (int o = 1; o < kBN; o <<= 1) {
        int y = (tid < kBN && tid >= o) ? scan_l[tid - o] : 0;
        __syncthreads();
        if (tid < kBN) { incl += y; scan_l[tid] = incl; }
        __syncthreads();
    }
    if (tid < kBN) {
        int cursor = p0 + incl - v;            // global position of node's run
        cnt_l[tid] = cursor;
        if (tid < nn) rp[base + tid] = cursor;
    }
    if (b == kNB - 1 && tid == 0) rp[kN] = p1;
    __syncthreads();

    // pass 2: col build + agg accumulate
    bool fits = (m <= kColCap);
    for (int i = p0 + tid; i < p1; i += 256) {
        unsigned int w = pairs[i];
        unsigned int s = w >> 6;
        int dloc = (int)(w & 63u);
        int pos = atomicAdd(&cnt_l[dloc], 1);
        if (fits) col_l[pos - p0] = (int)s;
        else      col[pos] = (int)s;           // rare fallback: 8KB-window scatter
        int sb = (s < (unsigned int)kNR) ? 0 : ((s < (unsigned int)(kNR + kNU)) ? 8 : 16);
        uint4 u = xpack[s];
        float2 q0 = bf2_to_f2(u.x), q1 = bf2_to_f2(u.y);
        float2 q2 = bf2_to_f2(u.z), q3 = bf2_to_f2(u.w);
        float* a = &agg_l[dloc][sb];
        atomicAdd(&a[0], q0.x); atomicAdd(&a[1], q0.y);
        atomicAdd(&a[2], q1.x); atomicAdd(&a[3], q1.y);
        atomicAdd(&a[4], q2.x); atomicAdd(&a[5], q2.y);
        atomicAdd(&a[6], q3.x); atomicAdd(&a[7], q3.y);
        atomicAdd(&agg_l[dloc][24 + (sb >> 3)], 1.f);
    }
    __syncthreads();
    if (fits) {
        for (int i = tid; i < m; i += 256) col[p0 + i] = col_l[i];   // coalesced
    }
    for (int i = tid; i < nn * 32; i += 256) {
        int n = i >> 5, sl = i & 31;
        agg[(size_t)(base + n) * kAS + sl] = (sl < 27) ? agg_l[n][sl] : 0.f;
    }
}

// ---------- dense via MFMA: one wave per 16 nodes (verified R7) ----------
__global__ void __launch_bounds__(256) gcn_dense(const float* __restrict__ agg,
                                                 const unsigned short* __restrict__ fwT,
                                                 const void* __restrict__ W2,
                                                 unsigned short* __restrict__ hw,
                                                 const int* __restrict__ flags) {
    __shared__ __align__(16) unsigned short sfwT[kF][40];
    __shared__ __align__(16) unsigned short sw2T[48][136];
    __shared__ __align__(16) unsigned short hbuf[4][16][136];
    int isbf = flags[0];
    int tid = threadIdx.x;
    for (int i = tid; i < kF * 32; i += 256) sfwT[i >> 5][i & 31] = fwT[i];
    for (int i = tid; i < 48 * kF; i += 256) {
        int c = i >> 7, k = i & 127;
        sw2T[c][k] = (c < kC) ? f_to_bf(ldf(W2, k * kC + c, isbf)) : (unsigned short)0;
    }
    __syncthreads();
    int wid = tid >> 6, lane = tid & 63;
    int T = blockIdx.x * 4 + wid;
    if (T >= kN / 16) return;
    int n0 = T * 16;
    int m = lane & 15, q = lane >> 4;

    const float* ar = agg + (size_t)(n0 + m) * kAS + q * 8;
    bf16x8 a1;
    #pragma unroll
    for (int i = 0; i < 8; i++) a1[i] = (short)f_to_bf(ar[i]);

    f32x4 c1[8];
    #pragma unroll
    for (int t = 0; t < 8; t++) {
        bf16x8 bfr = *(const bf16x8*)&sfwT[16 * t + m][q * 8];
        f32x4 z = {0.f, 0.f, 0.f, 0.f};
        c1[t] = __builtin_amdgcn_mfma_f32_16x16x32_bf16(a1, bfr, z, 0, 0, 0);
    }
    #pragma unroll
    for (int t = 0; t < 8; t++) {
        #pragma unroll
        for (int r = 0; r < 4; r++)
            hbuf[wid][q * 4 + r][16 * t + m] = f_to_bf(fmaxf(c1[t][r], 0.f));
    }
    f32x4 c2[3];
    #pragma unroll
    for (int t = 0; t < 3; t++) { c2[t].x = 0.f; c2[t].y = 0.f; c2[t].z = 0.f; c2[t].w = 0.f; }
    #pragma unroll
    for (int s = 0; s < 4; s++) {
        bf16x8 a2 = *(const bf16x8*)&hbuf[wid][m][s * 32 + q * 8];
        #pragma unroll
        for (int t = 0; t < 3; t++) {
            bf16x8 b2 = *(const bf16x8*)&sw2T[16 * t + m][s * 32 + q * 8];
            c2[t] = __builtin_amdgcn_mfma_f32_16x16x32_bf16(a2, b2, c2[t], 0, 0, 0);
        }
    }
    #pragma unroll
    for (int t = 0; t < 3; t++) {
        int cls = 16 * t + m;
        if (cls < kC) {
            #pragma unroll
            for (int r = 0; r < 4; r++)
                hw[(size_t)(n0 + q * 4 + r) * kC + cls] = f_to_bf(c2[t][r]);
        }
    }
}

// ---------- layer-2 gather: wave-per-node, 3 edge-groups x 20 class-lanes (R7-verified) ----------
__global__ void __launch_bounds__(256) gcn_gather2(const unsigned int* __restrict__ hw32,
                                                   const int* __restrict__ rp,
                                                   const int* __restrict__ col,
                                                   unsigned int* __restrict__ out,
                                                   const int* __restrict__ flags) {
    int isbf = flags[0];
    int w = (blockIdx.x * 256 + threadIdx.x) >> 6;
    if (w >= kN) return;
    int lane = threadIdx.x & 63;
    int grp = lane / 20;
    int c2  = lane % 20;
    int beg = rp[w], end = rp[w + 1];
    float ax = 0.f, ay = 0.f;
    if (grp < 3) {
        int e = beg + grp;
        for (; e + 3 < end; e += 6) {
            float2 f0 = bf2_to_f2(hw32[col[e]     * 20 + c2]);
            float2 f1 = bf2_to_f2(hw32[col[e + 3] * 20 + c2]);
            ax += f0.x + f1.x;  ay += f0.y + f1.y;
        }
        if (e < end) {
            float2 f = bf2_to_f2(hw32[col[e] * 20 + c2]);
            ax += f.x; ay += f.y;
        }
    }
    ax += __shfl(ax, lane + 20, 64) + __shfl(ax, lane + 40, 64);
    ay += __shfl(ay, lane + 20, 64) + __shfl(ay, lane + 40, 64);
    if (lane < 20) {
        if (isbf) {
            out[w * 20 + lane] = pack_bf2(ax, ay);
        } else {
            float* of = (float*)out;
            of[w * 40 + 2*lane]     = ax;
            of[w * 40 + 2*lane + 1] = ay;
        }
    }
}

extern "C" void kernel_launch(void* const* d_in, const int* in_sizes, int n_in,
                              void* d_out, int out_size, void* d_ws, size_t ws_size,
                              hipStream_t stream) {
    const void* xr = d_in[0];
    const void* xu = d_in[1];
    const void* xp = d_in[2];
    const int*  ei = (const int*)d_in[3];
    const void* Wr = d_in[4];
    const void* br = d_in[5];
    const void* Wu = d_in[6];
    const void* bu = d_in[7];
    const void* Wp = d_in[8];
    const void* bp = d_in[9];
    const void* W1 = d_in[10];
    const void* W2 = d_in[11];
    (void)in_sizes; (void)n_in; (void)out_size; (void)ws_size;

    char* ws = (char*)d_ws;
    size_t off = 0;
    auto alloc = [&](size_t bytes) -> void* {
        void* p = (void*)(ws + off);
        off = (off + bytes + 255) & ~(size_t)255;
        return p;
    };
    int*            flags  = (int*)           alloc(256);
    int*            cmat   = (int*)           alloc((size_t)kCH * kNBp * 4);  // 1.6 MB
    int*            reloff = (int*)           alloc((size_t)kNB * 256 * 4);   // 1.6 MB
    int*            btot   = (int*)           alloc((size_t)kNB * 4);
    int*            bbase  = (int*)           alloc((size_t)(kNB + 1) * 4);
    int*            rp     = (int*)           alloc((size_t)(kN + 1) * 4);
    unsigned short* fwT    = (unsigned short*)alloc(kF * 32 * 2);             // 8 KB
    uint4*          xpack  = (uint4*)         alloc((size_t)kN * 16);         // 1.6 MB
    unsigned int*   pairs  = (unsigned int*)  alloc((size_t)kE * 4);          // 6.4 MB
    int*            col    = (int*)           alloc((size_t)kE * 4);          // 6.4 MB
    unsigned short* hwb    = (unsigned short*)alloc((size_t)kN * kC * 2);     // 8 MB
    float*          agg    = (float*)         alloc((size_t)kN * kAS * 4);    // 12.8 MB

    gcn_sniff<<<1, 64, 0, stream>>>((const unsigned int*)W1, ei, flags);
    gcn_fuse<<<1, 128, 0, stream>>>(Wr, br, Wu, bu, Wp, bp, W1, fwT, flags);
    gcn_pack<<<(kN + 255) / 256, 256, 0, stream>>>(xr, xu, xp, xpack, flags);
    gcn_count<<<kCH, 512, 0, stream>>>(ei, cmat, flags);
    gcn_scanB1<<<kNB, 256, 0, stream>>>(cmat, reloff, btot);
    gcn_scanB2<<<1, 512, 0, stream>>>(btot, bbase);
    gcn_scatter<<<kCH, 512, 0, stream>>>(ei, bbase, reloff, pairs, flags);
    GCN_2190433321521_kernel<<<kNB, 256, 0, stream>>>(pairs, bbase, xpack, rp, col, agg);
    gcn_dense<<<(kN / 16 + 3) / 4, 256, 0, stream>>>(agg, fwT, W2, hwb, flags);
    gcn_gather2<<<(kN * 64 + 255) / 256, 256, 0, stream>>>((const unsigned int*)hwb, rp, col,
                                                           (unsigned int*)d_out, flags);
}